// Round 1
// baseline (2370.411 us; speedup 1.0000x reference)
//
#include <hip/hip_runtime.h>
#include <math.h>

#define Bn 128
#define Sn 4096
#define Dn 32
#define Hn 192
#define Kn 64
#define TB 64          // tokens per block (kernel 2)
#define AS 192         // LDS activation row stride (floats)
#define LOG2PI 1.8378770664093453f

// ---------------------------------------------------------------------------
// Kernel 1: the gated recurrence. One thread per (b,d) chain, scan over S.
// Stores the SHIFTED context: ctx[b][0][d] = context_init[d]; ctx[b][s+1][d]=h_s.
// ---------------------------------------------------------------------------
__global__ __launch_bounds__(64) void recurrence_kernel(
    const float* __restrict__ it_g, const float* __restrict__ W,
    const float* __restrict__ v,    const float* __restrict__ bia,
    const float* __restrict__ cinit, float* __restrict__ ctx)
{
    int g = blockIdx.x * 64 + threadIdx.x;   // 0..4095
    int b = g >> 5;                          // /32
    int d = g & 31;

    float w0 = W[d], w1 = W[32 + d], w2 = W[64 + d], w3 = W[96 + d];
    float vf = v[d], vr = v[32 + d];
    float bf = bia[d], br = bia[32 + d];

    const float* itp = it_g + (size_t)b * Sn;
    float* cp = ctx + ((size_t)b * Sn) * Dn + d;
    cp[0] = cinit[d];

    float c = 0.0f;
    float it_cur = itp[0];
    for (int s = 0; s < Sn; ++s) {
        float it_next = (s + 1 < Sn) ? itp[s + 1] : 0.0f;
        float feat = __logf(it_cur + 1e-8f);
        float u0 = feat * w0;
        float u1 = fmaf(feat, w1, bf);
        float u2 = fmaf(feat, w2, br);
        float u3 = feat * w3;
        // f = sigmoid(u1 + vf*c + bf); c_new = u0 + f*(c-u0)
        float xf = fmaf(vf, c, u1);
        float f  = 1.0f / (1.0f + __expf(-xf));
        float cn = fmaf(f, c - u0, u0);
        // r = sigmoid(u2 + vr*cn + br); h = u3 + r*(cn-u3)
        float xr = fmaf(vr, cn, u2);
        float r  = 1.0f / (1.0f + __expf(-xr));
        float h  = fmaf(r, cn - u3, u3);
        c = cn;
        if (s + 1 < Sn) cp[(size_t)(s + 1) * Dn] = h;
        it_cur = it_next;
    }
}

// ---------------------------------------------------------------------------
// Kernel 2: MLP (33 -> 192 -> 192 -> 192) + mixture logsumexp epilogue.
// 256 threads = 4 waves; wave wv owns tokens [wv*16, wv*16+16); lane n owns
// output cols {n, n+64, n+128}. Single LDS activation buffer, barrier-reuse.
// ---------------------------------------------------------------------------
__device__ __forceinline__ float wave_max(float x) {
#pragma unroll
    for (int o = 32; o >= 1; o >>= 1) x = fmaxf(x, __shfl_xor(x, o, 64));
    return x;
}
__device__ __forceinline__ float wave_sum(float x) {
#pragma unroll
    for (int o = 32; o >= 1; o >>= 1) x += __shfl_xor(x, o, 64);
    return x;
}

__global__ __launch_bounds__(256) void mlp_kernel(
    const float* __restrict__ it_g, const float* __restrict__ mask_g,
    const float* __restrict__ au_g, const float* __restrict__ ctx,
    const float* __restrict__ W1, const float* __restrict__ b1,
    const float* __restrict__ W2, const float* __restrict__ b2,
    const float* __restrict__ W3, const float* __restrict__ b3,
    float* __restrict__ out)
{
    __shared__ float A[TB * AS];
    __shared__ float wsums[4];

    const int tid  = threadIdx.x;
    const int lane = tid & 63;
    const int wv   = tid >> 6;
    const long tile = (long)blockIdx.x * TB;   // first token of tile
    const int b = (int)(tile >> 12);           // S = 4096 -> all tokens same b

    // ---- stage ctx tile (64 x 32 fp32) into LDS cols [0,32) ----
    {
        const float4* csrc = (const float4*)(ctx + (size_t)tile * Dn);
        for (int i = tid; i < TB * Dn / 4; i += 256) {
            float4 vv = csrc[i];
            int i4 = i * 4;
            int t = i4 >> 5;
            int k = i4 & 31;
            float* row = &A[t * AS + k];
            row[0] = vv.x; row[1] = vv.y; row[2] = vv.z; row[3] = vv.w;
        }
        // ages feature -> col 32
        for (int t = tid; t < TB; t += 256) {
            float itv = it_g[tile + t];
            float au  = au_g[tile + t];
            float ages = itv - itv * au;
            A[t * AS + 32] = __logf(ages + 1e-8f);
        }
    }
    __syncthreads();

    float acc[16][3];
    float* Arow = A + wv * 16 * AS;
    const float* Ab = Arow;

    auto init_bias = [&](const float* __restrict__ bp) {
        float bb0 = bp[lane], bb1 = bp[lane + 64], bb2 = bp[lane + 128];
#pragma unroll
        for (int t = 0; t < 16; ++t) { acc[t][0] = bb0; acc[t][1] = bb1; acc[t][2] = bb2; }
    };

    auto do_layer = [&](const float* __restrict__ Wp, int KIN) {
        for (int k = 0; k + 4 <= KIN; k += 4) {
            const float* wr = Wp + (size_t)k * Hn + lane;
            float w00 = wr[0],        w01 = wr[64],        w02 = wr[128];
            float w10 = wr[Hn],       w11 = wr[Hn + 64],   w12 = wr[Hn + 128];
            float w20 = wr[2 * Hn],   w21 = wr[2 * Hn + 64], w22 = wr[2 * Hn + 128];
            float w30 = wr[3 * Hn],   w31 = wr[3 * Hn + 64], w32 = wr[3 * Hn + 128];
#pragma unroll
            for (int t = 0; t < 16; ++t) {
                float4 a = *(const float4*)(Ab + t * AS + k);
                acc[t][0] = fmaf(a.x, w00, acc[t][0]); acc[t][1] = fmaf(a.x, w01, acc[t][1]); acc[t][2] = fmaf(a.x, w02, acc[t][2]);
                acc[t][0] = fmaf(a.y, w10, acc[t][0]); acc[t][1] = fmaf(a.y, w11, acc[t][1]); acc[t][2] = fmaf(a.y, w12, acc[t][2]);
                acc[t][0] = fmaf(a.z, w20, acc[t][0]); acc[t][1] = fmaf(a.z, w21, acc[t][1]); acc[t][2] = fmaf(a.z, w22, acc[t][2]);
                acc[t][0] = fmaf(a.w, w30, acc[t][0]); acc[t][1] = fmaf(a.w, w31, acc[t][1]); acc[t][2] = fmaf(a.w, w32, acc[t][2]);
            }
        }
        if (KIN & 3) {   // tail (only k=32 for KIN=33)
            int k = KIN & ~3;
            const float* wr = Wp + (size_t)k * Hn + lane;
            float w00 = wr[0], w01 = wr[64], w02 = wr[128];
#pragma unroll
            for (int t = 0; t < 16; ++t) {
                float a = Ab[t * AS + k];
                acc[t][0] = fmaf(a, w00, acc[t][0]); acc[t][1] = fmaf(a, w01, acc[t][1]); acc[t][2] = fmaf(a, w02, acc[t][2]);
            }
        }
    };

    auto write_relu = [&]() {
        __syncthreads();   // all waves done reading A
#pragma unroll
        for (int t = 0; t < 16; ++t) {
            float* row = Arow + t * AS;
            row[lane]       = fmaxf(acc[t][0], 0.0f);
            row[lane + 64]  = fmaxf(acc[t][1], 0.0f);
            row[lane + 128] = fmaxf(acc[t][2], 0.0f);
        }
        __syncthreads();   // outputs visible
    };

    init_bias(b1); do_layer(W1, 33);  write_relu();
    init_bias(b2); do_layer(W2, 192); write_relu();
    init_bias(b3); do_layer(W3, 192);
    // acc now holds raw: [t][0]=locs[lane], [t][1]=log_scales_raw[lane], [t][2]=w-logit[lane]

    // ---- mixture epilogue ----
    float psum = 0.0f;
#pragma unroll 1
    for (int t = 0; t < 16; ++t) {
        long tok = tile + wv * 16 + t;
        float loc = acc[t][0];
        float ls  = fminf(fmaxf(acc[t][1], -5.0f), 3.0f);
        float lg  = acc[t][2];

        // log_softmax over 64 lanes
        float m1 = wave_max(lg);
        float se = wave_sum(__expf(lg - m1));
        float lw = lg - (m1 + __logf(se));

        float itv = it_g[tok];
        float au  = au_g[tok];
        float mk  = mask_g[tok];
        float ages  = itv - itv * au;
        float resid = itv - ages;
        float tt = fmaxf(resid, 1e-10f);
        float y  = __logf(tt);

        float zs = (y - loc) * __expf(-ls);
        float comp = lw - ls - 0.5f * LOG2PI - 0.5f * zs * zs;

        float m2  = wave_max(comp);
        float se2 = wave_sum(__expf(comp - m2));
        float lp  = (m2 + __logf(se2) - y) * mk;
        psum += lp;
    }

    if (lane == 0) wsums[wv] = psum;
    __syncthreads();
    if (tid == 0) {
        float tot = wsums[0] + wsums[1] + wsums[2] + wsums[3];
        atomicAdd(&out[b], tot);
    }
}

// ---------------------------------------------------------------------------
extern "C" void kernel_launch(void* const* d_in, const int* in_sizes, int n_in,
                              void* d_out, int out_size, void* d_ws, size_t ws_size,
                              hipStream_t stream) {
    const float* it_g  = (const float*)d_in[0];
    const float* mask  = (const float*)d_in[1];
    const float* au    = (const float*)d_in[2];
    const float* W     = (const float*)d_in[3];
    const float* v     = (const float*)d_in[4];
    const float* bia   = (const float*)d_in[5];
    const float* cinit = (const float*)d_in[6];
    const float* W1    = (const float*)d_in[7];
    const float* b1    = (const float*)d_in[8];
    const float* W2    = (const float*)d_in[9];
    const float* b2    = (const float*)d_in[10];
    const float* W3    = (const float*)d_in[11];
    const float* b3    = (const float*)d_in[12];
    float* out = (float*)d_out;
    float* ctx = (float*)d_ws;   // B*S*D fp32 = 64 MB

    hipMemsetAsync(d_out, 0, (size_t)out_size * sizeof(float), stream);

    recurrence_kernel<<<(Bn * Dn) / 64, 64, 0, stream>>>(it_g, W, v, bia, cinit, ctx);

    mlp_kernel<<<(Bn * Sn) / TB, 256, 0, stream>>>(
        it_g, mask, au, ctx, W1, b1, W2, b2, W3, b3, out);
}

// Round 2
// 779.198 us; speedup vs baseline: 3.0421x; 3.0421x over previous
//
#include <hip/hip_runtime.h>
#include <math.h>

#define Bn 128
#define Sn 4096
#define Dn 32
#define Hn 192
#define NB 12              // 192/16 n-blocks
#define ASTR 232           // LDS stride (bf16 elems) for 192-col activations: 464B -> 8 banks, 2-way
#define A0STR 72           // LDS stride for 64-col layer-1 input: 144B -> 8 banks, 2-way
#define HALF_LOG2PI 0.9189385332046727f

typedef __attribute__((ext_vector_type(8))) short short8v;
typedef __attribute__((ext_vector_type(4))) float f32x4;

__device__ __forceinline__ unsigned short f2bf(float x) {
    unsigned int u = __float_as_uint(x);
    u += 0x7fffu + ((u >> 16) & 1u);   // RNE
    return (unsigned short)(u >> 16);
}

// ---------------------------------------------------------------------------
// Pack W1/W2/W3 (fp32 row-major [K][192]) into bf16 MFMA B-fragment order.
// frag fid covers (kstep=fid/12 within layer, nb=fid%12); within a frag,
// lane's 8 elems are W[k0+8*(lane>>4)+j][nb*16+(lane&15)], 16B contiguous.
// W1 K-padded 33 -> 64 with zeros. fid: 0..23 W1, 24..95 W2, 96..167 W3.
// ---------------------------------------------------------------------------
__global__ __launch_bounds__(64) void pack_weights(
    const float* __restrict__ W1, const float* __restrict__ W2,
    const float* __restrict__ W3, unsigned short* __restrict__ wp)
{
    int fid = blockIdx.x, lane = threadIdx.x;
    const float* Wsrc; int Krows, f;
    if (fid < 24)      { Wsrc = W1; Krows = 33;  f = fid; }
    else if (fid < 96) { Wsrc = W2; Krows = 192; f = fid - 24; }
    else               { Wsrc = W3; Krows = 192; f = fid - 96; }
    int kstep = f / NB, nb = f % NB;
    int k0 = kstep * 32 + 8 * (lane >> 4);
    int n  = nb * 16 + (lane & 15);
    short8v v;
#pragma unroll
    for (int j = 0; j < 8; ++j) {
        int k = k0 + j;
        float x = (k < Krows) ? Wsrc[k * Hn + n] : 0.0f;
        v[j] = (short)f2bf(x);
    }
    *(short8v*)(wp + (size_t)fid * 512 + lane * 8) = v;
}

// ---------------------------------------------------------------------------
// Recurrence: one thread per (b,d) chain. Batched float4 prefetch (8 steps),
// logs off the critical path; chain = fma -> v_exp -> add -> v_rcp -> fma.
// Writes SHIFTED context in bf16.
// ---------------------------------------------------------------------------
__global__ __launch_bounds__(64) void recurrence_kernel(
    const float* __restrict__ it_g, const float* __restrict__ W,
    const float* __restrict__ v,    const float* __restrict__ bia,
    const float* __restrict__ cinit, unsigned short* __restrict__ ctx)
{
    const float LOG2E = 1.4426950408889634f;
    int g = blockIdx.x * 64 + threadIdx.x;
    int b = g >> 5;
    int d = g & 31;

    float w0 = W[d], w3 = W[96 + d];
    float w1l = W[32 + d] * LOG2E, w2l = W[64 + d] * LOG2E;
    float vfl = v[d] * LOG2E,      vrl = v[32 + d] * LOG2E;
    float bfl = bia[d] * LOG2E,    brl = bia[32 + d] * LOG2E;

    const f32x4* itv = (const f32x4*)(it_g + (size_t)b * Sn);
    unsigned short* cp = ctx + ((size_t)b * Sn) * Dn + d;
    cp[0] = f2bf(cinit[d]);

    float c = 0.0f;
    f32x4 A0 = itv[0], A1 = itv[1];
    for (int blk = 0; blk < Sn / 8; ++blk) {
        f32x4 N0 = A0, N1 = A1;
        if (blk < Sn / 8 - 1) { N0 = itv[blk * 2 + 2]; N1 = itv[blk * 2 + 3]; }
        float feat[8];
#pragma unroll
        for (int j = 0; j < 4; ++j) {
            feat[j]     = __logf(A0[j] + 1e-8f);
            feat[j + 4] = __logf(A1[j] + 1e-8f);
        }
        unsigned short hb[8];
#pragma unroll
        for (int j = 0; j < 8; ++j) {
            float ft = feat[j];
            float u0 = ft * w0, u3 = ft * w3;
            float xfl = fmaf(ft, w1l, bfl);
            float xrl = fmaf(ft, w2l, brl);
            float sf = fmaf(vfl, c, xfl);
            float f_ = __builtin_amdgcn_rcpf(1.0f + exp2f(-sf));
            float cn = fmaf(f_, c - u0, u0);
            float sr = fmaf(vrl, cn, xrl);
            float r_ = __builtin_amdgcn_rcpf(1.0f + exp2f(-sr));
            float h  = fmaf(r_, cn - u3, u3);
            c = cn;
            hb[j] = f2bf(h);
        }
        int s0 = blk * 8;
#pragma unroll
        for (int j = 0; j < 8; ++j)
            if (s0 + j < Sn - 1) cp[(size_t)(s0 + j + 1) * Dn] = hb[j];
        A0 = N0; A1 = N1;
    }
}

// ---------------------------------------------------------------------------
// MLP via MFMA. 256 threads = 4 INDEPENDENT waves; wave owns 16 tokens.
// No __syncthreads anywhere: each wave reads only LDS it wrote.
// A-frag: row=lane&15 (token), k=ks*32+8*(lane>>4)+j. C: col=lane&15 (feature),
// row=4*(lane>>4)+reg (token).
// ---------------------------------------------------------------------------
__global__ __launch_bounds__(256) void mlp_kernel(
    const float* __restrict__ it_g, const float* __restrict__ mask_g,
    const float* __restrict__ au_g, const unsigned short* __restrict__ ctxb,
    const unsigned short* __restrict__ wp,
    const float* __restrict__ b1, const float* __restrict__ b2,
    const float* __restrict__ b3, float* __restrict__ out)
{
    __shared__ unsigned short A0s[4 * 16 * A0STR];
    __shared__ unsigned short As[4 * 16 * ASTR];

    const int tid = threadIdx.x;
    const int lane = tid & 63;
    const int wv = tid >> 6;
    const int gq = lane >> 4;     // k-group / token-subgroup
    const int cl = lane & 15;     // col (feature) / row (token) index
    const long tile = (long)blockIdx.x * 64;
    const long t0 = tile + wv * 16;
    const int b = (int)(tile >> 12);

    unsigned short* a0 = A0s + wv * (16 * A0STR);
    unsigned short* a  = As  + wv * (16 * ASTR);

    // ---- stage layer-1 input: ctx bf16 cols 0..31, ages col 32, zeros 33..63
    {
        int tok = lane >> 2, ch = lane & 3;
        *(short8v*)(a0 + tok * A0STR + ch * 8) =
            *(const short8v*)(ctxb + (t0 + tok) * Dn + ch * 8);
        float itv = it_g[t0 + tok];
        float auv = au_g[t0 + tok];
        float agesf = __logf(fmaf(-auv, itv, itv) + 1e-8f);
        short8v z = {0, 0, 0, 0, 0, 0, 0, 0};
        if (ch == 0) z[0] = (short)f2bf(agesf);
        *(short8v*)(a0 + tok * A0STR + 32 + ch * 8) = z;
    }

    f32x4 acc[NB];

    auto run_layer = [&](const unsigned short* ap, int astride, int nk,
                         const unsigned short* wpl, const float* __restrict__ bias) {
#pragma unroll
        for (int nb = 0; nb < NB; ++nb) {
            float bb = bias[nb * 16 + cl];
            acc[nb] = (f32x4){bb, bb, bb, bb};
        }
        for (int ks = 0; ks < nk; ++ks) {
            short8v af = *(const short8v*)(ap + cl * astride + ks * 32 + 8 * gq);
            const unsigned short* wk = wpl + (size_t)ks * (NB * 512) + lane * 8;
#pragma unroll
            for (int nb = 0; nb < NB; ++nb) {
                short8v bf = *(const short8v*)(wk + nb * 512);
                acc[nb] = __builtin_amdgcn_mfma_f32_16x16x32_bf16(af, bf, acc[nb], 0, 0, 0);
            }
        }
    };

    auto store_h = [&]() {
#pragma unroll
        for (int nb = 0; nb < NB; ++nb) {
            int col = nb * 16 + cl;
#pragma unroll
            for (int r = 0; r < 4; ++r)
                a[(4 * gq + r) * ASTR + col] = f2bf(fmaxf(acc[nb][r], 0.0f));
        }
    };

    run_layer(a0, A0STR, 2, wp,          b1); store_h();
    run_layer(a,  ASTR,  6, wp + 24 * 512, b2); store_h();
    run_layer(a,  ASTR,  6, wp + 96 * 512, b3);

    // ---- mixture epilogue: acc[0..3]=locs, acc[4..7]=log_scales, acc[8..11]=logits
    f32x4 it4 = *(const f32x4*)(it_g  + t0 + 4 * gq);
    f32x4 au4 = *(const f32x4*)(au_g  + t0 + 4 * gq);
    f32x4 mk4 = *(const f32x4*)(mask_g + t0 + 4 * gq);

    float psum = 0.0f;
#pragma unroll
    for (int r = 0; r < 4; ++r) {
        float lg0 = acc[8][r], lg1 = acc[9][r], lg2 = acc[10][r], lg3 = acc[11][r];
        float m1 = fmaxf(fmaxf(lg0, lg1), fmaxf(lg2, lg3));
#pragma unroll
        for (int m = 1; m < 16; m <<= 1) m1 = fmaxf(m1, __shfl_xor(m1, m, 64));
        float se = __expf(lg0 - m1) + __expf(lg1 - m1) + __expf(lg2 - m1) + __expf(lg3 - m1);
#pragma unroll
        for (int m = 1; m < 16; m <<= 1) se += __shfl_xor(se, m, 64);
        float lse1 = m1 + __logf(se);

        float itv = it4[r], auv = au4[r];
        float y = __logf(fmaxf(itv * auv, 1e-10f));   // resid = it*au

        float comp[4];
        float m2 = -1e30f;
#pragma unroll
        for (int nb = 0; nb < 4; ++nb) {
            float loc = acc[nb][r];
            float lsr = fminf(fmaxf(acc[4 + nb][r], -5.0f), 3.0f);
            float zs = (y - loc) * __expf(-lsr);
            comp[nb] = (acc[8 + nb][r] - lse1) - lsr - HALF_LOG2PI - 0.5f * zs * zs;
            m2 = fmaxf(m2, comp[nb]);
        }
#pragma unroll
        for (int m = 1; m < 16; m <<= 1) m2 = fmaxf(m2, __shfl_xor(m2, m, 64));
        float se2 = __expf(comp[0] - m2) + __expf(comp[1] - m2) +
                    __expf(comp[2] - m2) + __expf(comp[3] - m2);
#pragma unroll
        for (int m = 1; m < 16; m <<= 1) se2 += __shfl_xor(se2, m, 64);
        float lp = (m2 + __logf(se2) - y) * mk4[r];
        if (cl == 0) psum += lp;
    }
#pragma unroll
    for (int m = 1; m < 64; m <<= 1) psum += __shfl_xor(psum, m, 64);
    if (lane == 0) atomicAdd(out + b, psum);
}

// ---------------------------------------------------------------------------
extern "C" void kernel_launch(void* const* d_in, const int* in_sizes, int n_in,
                              void* d_out, int out_size, void* d_ws, size_t ws_size,
                              hipStream_t stream) {
    const float* it_g  = (const float*)d_in[0];
    const float* mask  = (const float*)d_in[1];
    const float* au    = (const float*)d_in[2];
    const float* W     = (const float*)d_in[3];
    const float* v     = (const float*)d_in[4];
    const float* bia   = (const float*)d_in[5];
    const float* cinit = (const float*)d_in[6];
    const float* W1    = (const float*)d_in[7];
    const float* b1    = (const float*)d_in[8];
    const float* W2    = (const float*)d_in[9];
    const float* b2    = (const float*)d_in[10];
    const float* W3    = (const float*)d_in[11];
    const float* b3    = (const float*)d_in[12];
    float* out = (float*)d_out;

    unsigned short* ctxb = (unsigned short*)d_ws;                 // 128*4096*32 bf16 = 32 MB
    unsigned short* wp   = ctxb + (size_t)Bn * Sn * Dn;           // 168 frags * 1 KB

    hipMemsetAsync(d_out, 0, (size_t)out_size * sizeof(float), stream);

    pack_weights<<<168, 64, 0, stream>>>(W1, W2, W3, wp);
    recurrence_kernel<<<(Bn * Dn) / 64, 64, 0, stream>>>(it_g, W, v, bia, cinit, ctxb);
    mlp_kernel<<<(Bn * Sn) / 64, 256, 0, stream>>>(
        it_g, mask, au, ctxb, wp, b1, b2, b3, out);
}

// Round 3
// 352.245 us; speedup vs baseline: 6.7294x; 2.2121x over previous
//
#include <hip/hip_runtime.h>
#include <math.h>

#define Bn 128
#define Sn 4096
#define Dn 32
#define Hn 192
#define NB 12              // 192/16 n-blocks
#define ASTR 232           // LDS stride (bf16) for 192-col activations: 2-way bank alias (free)
#define A0STR 72           // LDS stride for 64-col layer-1 input
#define CH 16              // recurrence chunks per chain
#define CHL 256            // steps per chunk (Sn/CH)
#define BURN 256           // burn-in steps (contractive warmup)
#define HALF_LOG2PI 0.9189385332046727f

typedef __attribute__((ext_vector_type(8))) short short8v;
typedef __attribute__((ext_vector_type(4))) float f32x4;

__device__ __forceinline__ unsigned short f2bf(float x) {
    unsigned int u = __float_as_uint(x);
    u += 0x7fffu + ((u >> 16) & 1u);   // RNE
    return (unsigned short)(u >> 16);
}

// ---------------------------------------------------------------------------
// Pack W1/W2/W3 (fp32 [K][192]) into bf16 MFMA B-fragment order.
// fid -> (layer, kstep, nb); lane's 8 elems: W[k0+8*(lane>>4)+j][nb*16+(lane&15)].
// ---------------------------------------------------------------------------
__global__ __launch_bounds__(64) void pack_weights(
    const float* __restrict__ W1, const float* __restrict__ W2,
    const float* __restrict__ W3, unsigned short* __restrict__ wp)
{
    int fid = blockIdx.x, lane = threadIdx.x;
    const float* Wsrc; int Krows, f;
    if (fid < 24)      { Wsrc = W1; Krows = 33;  f = fid; }
    else if (fid < 96) { Wsrc = W2; Krows = 192; f = fid - 24; }
    else               { Wsrc = W3; Krows = 192; f = fid - 96; }
    int kstep = f / NB, nb = f % NB;
    int k0 = kstep * 32 + 8 * (lane >> 4);
    int n  = nb * 16 + (lane & 15);
    short8v v;
#pragma unroll
    for (int j = 0; j < 8; ++j) {
        int k = k0 + j;
        float x = (k < Krows) ? Wsrc[k * Hn + n] : 0.0f;
        v[j] = (short)f2bf(x);
    }
    *(short8v*)(wp + (size_t)fid * 512 + lane * 8) = v;
}

// ---------------------------------------------------------------------------
// Recurrence, chunked: chain (b,d) split into CH chunks of CHL steps; each
// chunk burns in BURN steps from c=0 (contractive recurrence -> converges).
// Critical chain/step: fma -> v_exp -> add -> v_rcp -> fma (~35 cyc).
// ---------------------------------------------------------------------------
__global__ __launch_bounds__(256) void recurrence_kernel(
    const float* __restrict__ it_g, const float* __restrict__ W,
    const float* __restrict__ v,    const float* __restrict__ bia,
    const float* __restrict__ cinit, unsigned short* __restrict__ ctx)
{
    const float LOG2E = 1.4426950408889634f;
    int g = blockIdx.x * 256 + threadIdx.x;     // 0 .. Bn*Dn*CH-1
    int d = g & 31;
    int bc = g >> 5;                            // chunk*Bn + b
    int b = bc & (Bn - 1);
    int chunk = bc >> 7;                        // Bn=128

    float w0 = W[d], w3 = W[96 + d];
    // fold LOG2E and the exp negation into the constants:
    float nw1l = -W[32 + d] * LOG2E, nw2l = -W[64 + d] * LOG2E;
    float nvfl = -v[d] * LOG2E,      nvrl = -v[32 + d] * LOG2E;
    float nbfl = -bia[d] * LOG2E,    nbrl = -bia[32 + d] * LOG2E;

    const f32x4* itv = (const f32x4*)(it_g + (size_t)b * Sn);
    unsigned short* cp = ctx + ((size_t)b * Sn) * Dn + d;
    int s_start = chunk * CHL;
    int s_end   = s_start + CHL;
    int sbeg    = (chunk == 0) ? 0 : s_start - BURN;
    if (chunk == 0) cp[0] = f2bf(cinit[d]);

    float c = 0.0f;
    int blk0 = sbeg >> 3, blkN = s_end >> 3;
    f32x4 A0 = itv[blk0 * 2], A1 = itv[blk0 * 2 + 1];
    for (int blk = blk0; blk < blkN; ++blk) {
        f32x4 N0 = A0, N1 = A1;
        if (blk + 1 < blkN) { N0 = itv[blk * 2 + 2]; N1 = itv[blk * 2 + 3]; }
        float feat[8];
#pragma unroll
        for (int j = 0; j < 4; ++j) {
            feat[j]     = __logf(A0[j] + 1e-8f);
            feat[j + 4] = __logf(A1[j] + 1e-8f);
        }
        unsigned short hb[8];
#pragma unroll
        for (int j = 0; j < 8; ++j) {
            float ft = feat[j];
            float u0 = ft * w0, u3 = ft * w3;
            float nxfl = fmaf(ft, nw1l, nbfl);     // -(u1+bf)*log2e
            float nxrl = fmaf(ft, nw2l, nbrl);
            // f = 1/(1+2^(-xf*log2e))
            float sfn = fmaf(nvfl, c, nxfl);
            float ef  = __builtin_amdgcn_exp2f(sfn);
            float f_  = __builtin_amdgcn_rcpf(1.0f + ef);
            float cmu = c - u0;                     // parallel with exp chain
            float cn  = fmaf(f_, cmu, u0);
            float srn = fmaf(nvrl, cn, nxrl);
            float er  = __builtin_amdgcn_exp2f(srn);
            float r_  = __builtin_amdgcn_rcpf(1.0f + er);
            float h   = fmaf(r_, cn - u3, u3);
            c = cn;
            hb[j] = f2bf(h);
        }
        int s0 = blk * 8;
        if (s0 >= s_start) {                        // wave-uniform
#pragma unroll
            for (int j = 0; j < 8; ++j)
                if (s0 + j + 1 < Sn) cp[(size_t)(s0 + j + 1) * Dn] = hb[j];
        }
        A0 = N0; A1 = N1;
    }
}

// ---------------------------------------------------------------------------
// MLP via MFMA. 256 threads = 4 independent waves; each wave owns 32 tokens
// (M=2 row-frags) -> every B-frag load feeds 2 MFMAs. No __syncthreads.
// ---------------------------------------------------------------------------
__global__ __launch_bounds__(256) void mlp_kernel(
    const float* __restrict__ it_g, const float* __restrict__ mask_g,
    const float* __restrict__ au_g, const unsigned short* __restrict__ ctxb,
    const unsigned short* __restrict__ wp,
    const float* __restrict__ b1, const float* __restrict__ b2,
    const float* __restrict__ b3, float* __restrict__ out)
{
    __shared__ unsigned short A0s[4 * 32 * A0STR];
    __shared__ unsigned short As[4 * 32 * ASTR];

    const int tid = threadIdx.x;
    const int lane = tid & 63;
    const int wv = tid >> 6;
    const int gq = lane >> 4;     // k-group / token-subgroup
    const int cl = lane & 15;     // col (feature) / row (token) index
    const long tile = (long)blockIdx.x * 128;
    const long t0 = tile + wv * 32;
    const int b = (int)(tile >> 12);

    unsigned short* a0 = A0s + wv * (32 * A0STR);
    unsigned short* a  = As  + wv * (32 * ASTR);

    // ---- stage layer-1 input: ctx cols 0..31, age col 32, zeros 33..63
#pragma unroll
    for (int half = 0; half < 2; ++half) {
        int tok = half * 16 + (lane >> 2), chq = lane & 3;
        *(short8v*)(a0 + tok * A0STR + chq * 8) =
            *(const short8v*)(ctxb + (t0 + tok) * Dn + chq * 8);
        float itv = it_g[t0 + tok];
        float auv = au_g[t0 + tok];
        float agesf = __logf(fmaf(-auv, itv, itv) + 1e-8f);
        short8v z = {0, 0, 0, 0, 0, 0, 0, 0};
        if (chq == 0) z[0] = (short)f2bf(agesf);
        *(short8v*)(a0 + tok * A0STR + 32 + chq * 8) = z;
    }

    f32x4 acc0[NB], acc1[NB];

    auto run_layer = [&](const unsigned short* ap, int astride, int nk,
                         const unsigned short* wpl, const float* __restrict__ bias) {
#pragma unroll
        for (int nb = 0; nb < NB; ++nb) {
            float bb = bias[nb * 16 + cl];
            acc0[nb] = (f32x4){bb, bb, bb, bb};
            acc1[nb] = (f32x4){bb, bb, bb, bb};
        }
        for (int ks = 0; ks < nk; ++ks) {
            short8v af0 = *(const short8v*)(ap + cl * astride + ks * 32 + 8 * gq);
            short8v af1 = *(const short8v*)(ap + (16 + cl) * astride + ks * 32 + 8 * gq);
            const unsigned short* wk = wpl + (size_t)ks * (NB * 512) + lane * 8;
#pragma unroll
            for (int nb = 0; nb < NB; ++nb) {
                short8v bfv = *(const short8v*)(wk + nb * 512);
                acc0[nb] = __builtin_amdgcn_mfma_f32_16x16x32_bf16(af0, bfv, acc0[nb], 0, 0, 0);
                acc1[nb] = __builtin_amdgcn_mfma_f32_16x16x32_bf16(af1, bfv, acc1[nb], 0, 0, 0);
            }
        }
    };

    auto store_h = [&]() {
#pragma unroll
        for (int nb = 0; nb < NB; ++nb) {
            int col = nb * 16 + cl;
#pragma unroll
            for (int r = 0; r < 4; ++r) {
                a[(4 * gq + r) * ASTR + col]        = f2bf(fmaxf(acc0[nb][r], 0.0f));
                a[(16 + 4 * gq + r) * ASTR + col]   = f2bf(fmaxf(acc1[nb][r], 0.0f));
            }
        }
    };

    run_layer(a0, A0STR, 2, wp,           b1); store_h();
    run_layer(a,  ASTR,  6, wp + 24 * 512, b2); store_h();
    run_layer(a,  ASTR,  6, wp + 96 * 512, b3);

    // ---- mixture epilogue: acc[0..3]=locs, [4..7]=log_scales, [8..11]=logits
    float psum = 0.0f;
#pragma unroll
    for (int m = 0; m < 2; ++m) {
        f32x4* ac = m ? acc1 : acc0;
        long tm = t0 + m * 16;
        f32x4 it4 = *(const f32x4*)(it_g   + tm + 4 * gq);
        f32x4 au4 = *(const f32x4*)(au_g   + tm + 4 * gq);
        f32x4 mk4 = *(const f32x4*)(mask_g + tm + 4 * gq);
#pragma unroll
        for (int r = 0; r < 4; ++r) {
            float lg0 = ac[8][r], lg1 = ac[9][r], lg2 = ac[10][r], lg3 = ac[11][r];
            float m1 = fmaxf(fmaxf(lg0, lg1), fmaxf(lg2, lg3));
#pragma unroll
            for (int mm = 1; mm < 16; mm <<= 1) m1 = fmaxf(m1, __shfl_xor(m1, mm, 64));
            float se = __expf(lg0 - m1) + __expf(lg1 - m1) + __expf(lg2 - m1) + __expf(lg3 - m1);
#pragma unroll
            for (int mm = 1; mm < 16; mm <<= 1) se += __shfl_xor(se, mm, 64);
            float lse1 = m1 + __logf(se);

            float itv = it4[r], auv = au4[r];
            float y = __logf(fmaxf(itv * auv, 1e-10f));   // resid = it*au

            float comp[4];
            float m2 = -1e30f;
#pragma unroll
            for (int nb = 0; nb < 4; ++nb) {
                float loc = ac[nb][r];
                float lsr = fminf(fmaxf(ac[4 + nb][r], -5.0f), 3.0f);
                float zs = (y - loc) * __expf(-lsr);
                comp[nb] = (ac[8 + nb][r] - lse1) - lsr - HALF_LOG2PI - 0.5f * zs * zs;
                m2 = fmaxf(m2, comp[nb]);
            }
#pragma unroll
            for (int mm = 1; mm < 16; mm <<= 1) m2 = fmaxf(m2, __shfl_xor(m2, mm, 64));
            float se2 = __expf(comp[0] - m2) + __expf(comp[1] - m2) +
                        __expf(comp[2] - m2) + __expf(comp[3] - m2);
#pragma unroll
            for (int mm = 1; mm < 16; mm <<= 1) se2 += __shfl_xor(se2, mm, 64);
            float lp = (m2 + __logf(se2) - y) * mk4[r];
            if (cl == 0) psum += lp;
        }
    }
#pragma unroll
    for (int mm = 1; mm < 64; mm <<= 1) psum += __shfl_xor(psum, mm, 64);
    if (lane == 0) atomicAdd(out + b, psum);
}

// ---------------------------------------------------------------------------
extern "C" void kernel_launch(void* const* d_in, const int* in_sizes, int n_in,
                              void* d_out, int out_size, void* d_ws, size_t ws_size,
                              hipStream_t stream) {
    const float* it_g  = (const float*)d_in[0];
    const float* mask  = (const float*)d_in[1];
    const float* au    = (const float*)d_in[2];
    const float* W     = (const float*)d_in[3];
    const float* v     = (const float*)d_in[4];
    const float* bia   = (const float*)d_in[5];
    const float* cinit = (const float*)d_in[6];
    const float* W1    = (const float*)d_in[7];
    const float* b1    = (const float*)d_in[8];
    const float* W2    = (const float*)d_in[9];
    const float* b2    = (const float*)d_in[10];
    const float* W3    = (const float*)d_in[11];
    const float* b3    = (const float*)d_in[12];
    float* out = (float*)d_out;

    unsigned short* ctxb = (unsigned short*)d_ws;                 // 32 MB
    unsigned short* wp   = ctxb + (size_t)Bn * Sn * Dn;           // 168 KB

    hipMemsetAsync(d_out, 0, (size_t)out_size * sizeof(float), stream);

    pack_weights<<<168, 64, 0, stream>>>(W1, W2, W3, wp);
    recurrence_kernel<<<(Bn * Dn * CH) / 256, 256, 0, stream>>>(
        it_g, W, v, bia, cinit, ctxb);
    mlp_kernel<<<(Bn * Sn) / 128, 256, 0, stream>>>(
        it_g, mask, au, ctxb, wp, b1, b2, b3, out);
}

// Round 4
// 336.421 us; speedup vs baseline: 7.0460x; 1.0470x over previous
//
#include <hip/hip_runtime.h>
#include <math.h>

#define Bn 128
#define Sn 4096
#define Dn 32
#define Hn 192
#define NB 12
#define ASTR 200           // LDS act stride (bf16 elems)
#define A0STR 72           // LDS stride for 64-col layer-1 input
#define CH 16              // recurrence chunks per chain
#define CHL 256            // steps per chunk
#define BURN 256           // burn-in steps
#define HALF_LOG2PI 0.9189385332046727f

typedef __attribute__((ext_vector_type(8))) short short8v;
typedef __attribute__((ext_vector_type(4))) float f32x4;

__device__ __forceinline__ unsigned short f2bf(float x) {
    unsigned int u = __float_as_uint(x);
    u += 0x7fffu + ((u >> 16) & 1u);   // RNE
    return (unsigned short)(u >> 16);
}

// ---------------------------------------------------------------------------
// Pack W1/W2/W3 (fp32 [K][192]) into bf16 MFMA B-fragment order.
// fid = layerbase + kstep*12 + nb; lane's 8 elems: W[k0+8*(lane>>4)+j][nb*16+(lane&15)].
// ---------------------------------------------------------------------------
__global__ __launch_bounds__(64) void pack_weights(
    const float* __restrict__ W1, const float* __restrict__ W2,
    const float* __restrict__ W3, unsigned short* __restrict__ wp)
{
    int fid = blockIdx.x, lane = threadIdx.x;
    const float* Wsrc; int Krows, f;
    if (fid < 24)      { Wsrc = W1; Krows = 33;  f = fid; }
    else if (fid < 96) { Wsrc = W2; Krows = 192; f = fid - 24; }
    else               { Wsrc = W3; Krows = 192; f = fid - 96; }
    int kstep = f / NB, nb = f % NB;
    int k0 = kstep * 32 + 8 * (lane >> 4);
    int n  = nb * 16 + (lane & 15);
    short8v v;
#pragma unroll
    for (int j = 0; j < 8; ++j) {
        int k = k0 + j;
        float x = (k < Krows) ? Wsrc[k * Hn + n] : 0.0f;
        v[j] = (short)f2bf(x);
    }
    *(short8v*)(wp + (size_t)fid * 512 + lane * 8) = v;
}

// ---------------------------------------------------------------------------
// Recurrence, chunked (contractive burn-in). Unchanged from R3 (~30us).
// ---------------------------------------------------------------------------
__global__ __launch_bounds__(256) void recurrence_kernel(
    const float* __restrict__ it_g, const float* __restrict__ W,
    const float* __restrict__ v,    const float* __restrict__ bia,
    const float* __restrict__ cinit, unsigned short* __restrict__ ctx)
{
    const float LOG2E = 1.4426950408889634f;
    int g = blockIdx.x * 256 + threadIdx.x;
    int d = g & 31;
    int bc = g >> 5;
    int b = bc & (Bn - 1);
    int chunk = bc >> 7;

    float w0 = W[d], w3 = W[96 + d];
    float nw1l = -W[32 + d] * LOG2E, nw2l = -W[64 + d] * LOG2E;
    float nvfl = -v[d] * LOG2E,      nvrl = -v[32 + d] * LOG2E;
    float nbfl = -bia[d] * LOG2E,    nbrl = -bia[32 + d] * LOG2E;

    const f32x4* itv = (const f32x4*)(it_g + (size_t)b * Sn);
    unsigned short* cp = ctx + ((size_t)b * Sn) * Dn + d;
    int s_start = chunk * CHL;
    int s_end   = s_start + CHL;
    int sbeg    = (chunk == 0) ? 0 : s_start - BURN;
    if (chunk == 0) cp[0] = f2bf(cinit[d]);

    float c = 0.0f;
    int blk0 = sbeg >> 3, blkN = s_end >> 3;
    f32x4 A0 = itv[blk0 * 2], A1 = itv[blk0 * 2 + 1];
    for (int blk = blk0; blk < blkN; ++blk) {
        f32x4 N0 = A0, N1 = A1;
        if (blk + 1 < blkN) { N0 = itv[blk * 2 + 2]; N1 = itv[blk * 2 + 3]; }
        float feat[8];
#pragma unroll
        for (int j = 0; j < 4; ++j) {
            feat[j]     = __logf(A0[j] + 1e-8f);
            feat[j + 4] = __logf(A1[j] + 1e-8f);
        }
        unsigned short hb[8];
#pragma unroll
        for (int j = 0; j < 8; ++j) {
            float ft = feat[j];
            float u0 = ft * w0, u3 = ft * w3;
            float nxfl = fmaf(ft, nw1l, nbfl);
            float nxrl = fmaf(ft, nw2l, nbrl);
            float sfn = fmaf(nvfl, c, nxfl);
            float ef  = __builtin_amdgcn_exp2f(sfn);
            float f_  = __builtin_amdgcn_rcpf(1.0f + ef);
            float cmu = c - u0;
            float cn  = fmaf(f_, cmu, u0);
            float srn = fmaf(nvrl, cn, nxrl);
            float er  = __builtin_amdgcn_exp2f(srn);
            float r_  = __builtin_amdgcn_rcpf(1.0f + er);
            float h   = fmaf(r_, cn - u3, u3);
            c = cn;
            hb[j] = f2bf(h);
        }
        int s0 = blk * 8;
        if (s0 >= s_start) {
#pragma unroll
            for (int j = 0; j < 8; ++j)
                if (s0 + j + 1 < Sn) cp[(size_t)(s0 + j + 1) * Dn] = hb[j];
        }
        A0 = N0; A1 = N1;
    }
}

// ---------------------------------------------------------------------------
// MLP: 128-thread block = 2 waves, 32 tokens. Each wave computes 6 of 12
// n-blocks (halves VGPR + weight traffic); activations shared via LDS.
// Epilogue: f32 LDS exchange so each wave finishes one 16-token panel.
// ---------------------------------------------------------------------------
__global__ __launch_bounds__(128, 4) void mlp_kernel(
    const float* __restrict__ it_g, const float* __restrict__ mask_g,
    const float* __restrict__ au_g, const unsigned short* __restrict__ ctxb,
    const unsigned short* __restrict__ wp,
    const float* __restrict__ b1, const float* __restrict__ b2,
    const float* __restrict__ b3, float* __restrict__ out)
{
    __shared__ unsigned short A0s[32 * A0STR];     // 4.6 KB
    __shared__ unsigned short Acts[32 * ASTR];     // 12.8 KB (reused f32 exch)

    const int tid = threadIdx.x;
    const int lane = tid & 63;
    const int wv = tid >> 6;          // 0 or 1
    const int gq = lane >> 4;
    const int cl = lane & 15;
    const long tile = (long)blockIdx.x * 32;
    const int b = (int)(tile >> 12);
    const int nbase = wv * 6;

    // ---- stage layer-1 input: ctx cols 0..31, age col 32, zeros 33..63 ----
    {
        int tok = tid >> 2, ch = tid & 3;
        *(short8v*)(A0s + tok * A0STR + ch * 8) =
            *(const short8v*)(ctxb + (tile + tok) * Dn + ch * 8);
        short8v z = {0, 0, 0, 0, 0, 0, 0, 0};
        if (ch == 0) {
            float itv = it_g[tile + tok];
            float auv = au_g[tile + tok];
            z[0] = (short)f2bf(__logf(fmaf(-auv, itv, itv) + 1e-8f));
        }
        *(short8v*)(A0s + tok * A0STR + 32 + ch * 8) = z;
    }
    __syncthreads();

    f32x4 acc0[6], acc1[6];

    auto run_layer = [&](const unsigned short* ap, int astride, int nk,
                         const unsigned short* wpl, const float* __restrict__ bias) {
#pragma unroll
        for (int j = 0; j < 6; ++j) {
            float bb = bias[(nbase + j) * 16 + cl];
            acc0[j] = (f32x4){bb, bb, bb, bb};
            acc1[j] = (f32x4){bb, bb, bb, bb};
        }
        for (int ks = 0; ks < nk; ++ks) {
            short8v af0 = *(const short8v*)(ap + cl * astride + ks * 32 + 8 * gq);
            short8v af1 = *(const short8v*)(ap + (16 + cl) * astride + ks * 32 + 8 * gq);
            const unsigned short* wk = wpl + ((size_t)ks * 12 + nbase) * 512 + lane * 8;
#pragma unroll
            for (int j = 0; j < 6; ++j) {
                short8v bfv = *(const short8v*)(wk + j * 512);
                acc0[j] = __builtin_amdgcn_mfma_f32_16x16x32_bf16(af0, bfv, acc0[j], 0, 0, 0);
                acc1[j] = __builtin_amdgcn_mfma_f32_16x16x32_bf16(af1, bfv, acc1[j], 0, 0, 0);
            }
        }
    };

    auto store_h = [&]() {
#pragma unroll
        for (int j = 0; j < 6; ++j) {
            int col = (nbase + j) * 16 + cl;
#pragma unroll
            for (int r = 0; r < 4; ++r) {
                Acts[(4 * gq + r) * ASTR + col]      = f2bf(fmaxf(acc0[j][r], 0.0f));
                Acts[(16 + 4 * gq + r) * ASTR + col] = f2bf(fmaxf(acc1[j][r], 0.0f));
            }
        }
    };

    run_layer(A0s, A0STR, 2, wp, b1);
    store_h();                       // Acts first write; A0s untouched
    __syncthreads();                 // L1 outputs visible
    run_layer(Acts, ASTR, 6, wp + 24 * 512, b2);
    __syncthreads();                 // all L2 reads done
    store_h();
    __syncthreads();                 // L2 outputs visible
    run_layer(Acts, ASTR, 6, wp + 96 * 512, b3);

    // prefetch epilogue scalars (wave's own 16-token panel)
    const long tm = tile + 16 * wv + 4 * gq;
    f32x4 it4 = *(const f32x4*)(it_g   + tm);
    f32x4 au4 = *(const f32x4*)(au_g   + tm);
    f32x4 mk4 = *(const f32x4*)(mask_g + tm);

    __syncthreads();                 // all L3 reads done; Acts reusable as f32

    // ---- exchange complementary accs: wave0 keeps panel0 (acc0), wave1 panel1
    float* X = (float*)Acts;         // 2 regions x 1536 floats = 12288 B
    {
#pragma unroll
        for (int j = 0; j < 6; ++j) {
            f32x4 src = wv ? acc0[j] : acc1[j];
            *(f32x4*)(X + wv * 1536 + j * 256 + lane * 4) = src;
        }
    }
    __syncthreads();

    f32x4 ac[12];
    {
        f32x4 oth[6];
#pragma unroll
        for (int j = 0; j < 6; ++j)
            oth[j] = *(const f32x4*)(X + (1 - wv) * 1536 + j * 256 + lane * 4);
        if (wv == 0) {
#pragma unroll
            for (int j = 0; j < 6; ++j) { ac[j] = acc0[j]; ac[6 + j] = oth[j]; }
        } else {
#pragma unroll
            for (int j = 0; j < 6; ++j) { ac[j] = oth[j]; ac[6 + j] = acc1[j]; }
        }
    }

    // ---- mixture epilogue: ac[0..3]=locs, [4..7]=log_scales, [8..11]=logits
    float psum = 0.0f;
#pragma unroll
    for (int r = 0; r < 4; ++r) {
        float lg0 = ac[8][r], lg1 = ac[9][r], lg2 = ac[10][r], lg3 = ac[11][r];
        float m1 = fmaxf(fmaxf(lg0, lg1), fmaxf(lg2, lg3));
#pragma unroll
        for (int mm = 1; mm < 16; mm <<= 1) m1 = fmaxf(m1, __shfl_xor(m1, mm, 64));
        float se = __expf(lg0 - m1) + __expf(lg1 - m1) + __expf(lg2 - m1) + __expf(lg3 - m1);
#pragma unroll
        for (int mm = 1; mm < 16; mm <<= 1) se += __shfl_xor(se, mm, 64);
        float lse1 = m1 + __logf(se);

        float itv = it4[r], auv = au4[r];
        float y = __logf(fmaxf(itv * auv, 1e-10f));   // resid = it*au

        float comp[4];
        float m2 = -1e30f;
#pragma unroll
        for (int nb = 0; nb < 4; ++nb) {
            float loc = ac[nb][r];
            float lsr = fminf(fmaxf(ac[4 + nb][r], -5.0f), 3.0f);
            float zs = (y - loc) * __expf(-lsr);
            comp[nb] = (ac[8 + nb][r] - lse1) - lsr - HALF_LOG2PI - 0.5f * zs * zs;
            m2 = fmaxf(m2, comp[nb]);
        }
#pragma unroll
        for (int mm = 1; mm < 16; mm <<= 1) m2 = fmaxf(m2, __shfl_xor(m2, mm, 64));
        float se2 = __expf(comp[0] - m2) + __expf(comp[1] - m2) +
                    __expf(comp[2] - m2) + __expf(comp[3] - m2);
#pragma unroll
        for (int mm = 1; mm < 16; mm <<= 1) se2 += __shfl_xor(se2, mm, 64);
        float lp = (m2 + __logf(se2) - y) * mk4[r];
        if (cl == 0) psum += lp;
    }
#pragma unroll
    for (int mm = 1; mm < 64; mm <<= 1) psum += __shfl_xor(psum, mm, 64);
    if (lane == 0) atomicAdd(out + b, psum);
}

// ---------------------------------------------------------------------------
extern "C" void kernel_launch(void* const* d_in, const int* in_sizes, int n_in,
                              void* d_out, int out_size, void* d_ws, size_t ws_size,
                              hipStream_t stream) {
    const float* it_g  = (const float*)d_in[0];
    const float* mask  = (const float*)d_in[1];
    const float* au    = (const float*)d_in[2];
    const float* W     = (const float*)d_in[3];
    const float* v     = (const float*)d_in[4];
    const float* bia   = (const float*)d_in[5];
    const float* cinit = (const float*)d_in[6];
    const float* W1    = (const float*)d_in[7];
    const float* b1    = (const float*)d_in[8];
    const float* W2    = (const float*)d_in[9];
    const float* b2    = (const float*)d_in[10];
    const float* W3    = (const float*)d_in[11];
    const float* b3    = (const float*)d_in[12];
    float* out = (float*)d_out;

    unsigned short* ctxb = (unsigned short*)d_ws;                 // 32 MB
    unsigned short* wp   = ctxb + (size_t)Bn * Sn * Dn;           // 168 KB

    hipMemsetAsync(d_out, 0, (size_t)out_size * sizeof(float), stream);

    pack_weights<<<168, 64, 0, stream>>>(W1, W2, W3, wp);
    recurrence_kernel<<<(Bn * Dn * CH) / 256, 256, 0, stream>>>(
        it_g, W, v, bia, cinit, ctxb);
    mlp_kernel<<<(Bn * Sn) / 32, 128, 0, stream>>>(
        it_g, mask, au, ctxb, wp, b1, b2, b3, out);
}

// Round 5
// 235.106 us; speedup vs baseline: 10.0823x; 1.4309x over previous
//
#include <hip/hip_runtime.h>
#include <math.h>
#include <type_traits>

#define Bn 128
#define Sn 4096
#define Dn 32
#define Hn 192
#define ASTR 196           // LDS act stride (bf16): 98 dwords %32 = 2 -> 2-way max
#define A0STR 68           // layer-1 input stride: 34 dwords %32 = 2
#define CH 32              // recurrence chunks per chain
#define CHL 128            // steps per chunk
#define BURN 128           // burn-in steps
#define HALF_LOG2PI 0.9189385332046727f

typedef __attribute__((ext_vector_type(8))) short short8v;
typedef __attribute__((ext_vector_type(4))) float f32x4;

__device__ __forceinline__ unsigned short f2bf(float x) {
    return (unsigned short)((__float_as_uint(x) + 0x8000u) >> 16);
}

// ---------------------------------------------------------------------------
// Pack W1/W2/W3 (fp32 [K][192]) into bf16 MFMA B-fragment order.
// ---------------------------------------------------------------------------
__global__ __launch_bounds__(64) void pack_weights(
    const float* __restrict__ W1, const float* __restrict__ W2,
    const float* __restrict__ W3, unsigned short* __restrict__ wp)
{
    int fid = blockIdx.x, lane = threadIdx.x;
    const float* Wsrc; int Krows, f;
    if (fid < 24)      { Wsrc = W1; Krows = 33;  f = fid; }
    else if (fid < 96) { Wsrc = W2; Krows = 192; f = fid - 24; }
    else               { Wsrc = W3; Krows = 192; f = fid - 96; }
    int kstep = f / 12, nb = f % 12;
    int k0 = kstep * 32 + 8 * (lane >> 4);
    int n  = nb * 16 + (lane & 15);
    short8v v;
#pragma unroll
    for (int j = 0; j < 8; ++j) {
        int k = k0 + j;
        float x = (k < Krows) ? Wsrc[k * Hn + n] : 0.0f;
        v[j] = (short)f2bf(x);
    }
    *(short8v*)(wp + (size_t)fid * 512 + lane * 8) = v;
}

// ---------------------------------------------------------------------------
// Recurrence, chunked (contractive burn-in).
// ---------------------------------------------------------------------------
__global__ __launch_bounds__(256) void recurrence_kernel(
    const float* __restrict__ it_g, const float* __restrict__ W,
    const float* __restrict__ v,    const float* __restrict__ bia,
    const float* __restrict__ cinit, unsigned short* __restrict__ ctx)
{
    const float LOG2E = 1.4426950408889634f;
    int g = blockIdx.x * 256 + threadIdx.x;
    int d = g & 31;
    int bc = g >> 5;
    int b = bc & (Bn - 1);
    int chunk = bc >> 7;

    float w0 = W[d], w3 = W[96 + d];
    float nw1l = -W[32 + d] * LOG2E, nw2l = -W[64 + d] * LOG2E;
    float nvfl = -v[d] * LOG2E,      nvrl = -v[32 + d] * LOG2E;
    float nbfl = -bia[d] * LOG2E,    nbrl = -bia[32 + d] * LOG2E;

    const f32x4* itv = (const f32x4*)(it_g + (size_t)b * Sn);
    unsigned short* cp = ctx + ((size_t)b * Sn) * Dn + d;
    int s_start = chunk * CHL;
    int s_end   = s_start + CHL;
    int sbeg    = (chunk == 0) ? 0 : s_start - BURN;
    if (chunk == 0) cp[0] = f2bf(cinit[d]);

    float c = 0.0f;
    int blk0 = sbeg >> 3, blkN = s_end >> 3;
    f32x4 A0 = itv[blk0 * 2], A1 = itv[blk0 * 2 + 1];
    for (int blk = blk0; blk < blkN; ++blk) {
        f32x4 N0 = A0, N1 = A1;
        if (blk + 1 < blkN) { N0 = itv[blk * 2 + 2]; N1 = itv[blk * 2 + 3]; }
        float feat[8];
#pragma unroll
        for (int j = 0; j < 4; ++j) {
            feat[j]     = __logf(A0[j] + 1e-8f);
            feat[j + 4] = __logf(A1[j] + 1e-8f);
        }
        unsigned short hb[8];
#pragma unroll
        for (int j = 0; j < 8; ++j) {
            float ft = feat[j];
            float u0 = ft * w0, u3 = ft * w3;
            float nxfl = fmaf(ft, nw1l, nbfl);
            float nxrl = fmaf(ft, nw2l, nbrl);
            float sfn = fmaf(nvfl, c, nxfl);
            float ef  = __builtin_amdgcn_exp2f(sfn);
            float f_  = __builtin_amdgcn_rcpf(1.0f + ef);
            float cmu = c - u0;
            float cn  = fmaf(f_, cmu, u0);
            float srn = fmaf(nvrl, cn, nxrl);
            float er  = __builtin_amdgcn_exp2f(srn);
            float r_  = __builtin_amdgcn_rcpf(1.0f + er);
            float h   = fmaf(r_, cn - u3, u3);
            c = cn;
            hb[j] = f2bf(h);
        }
        int s0 = blk * 8;
        if (s0 >= s_start) {
#pragma unroll
            for (int j = 0; j < 8; ++j)
                if (s0 + j + 1 < Sn) cp[(size_t)(s0 + j + 1) * Dn] = hb[j];
        }
        A0 = N0; A1 = N1;
    }
}

// ---------------------------------------------------------------------------
// MLP: 128 threads = 2 waves; block covers 64 tokens. Wave wv computes
// n-blocks [6wv, 6wv+6) for ALL 64 tokens (M=4 row-frags per wave).
// Single LDS buffer (A0 view aliases Acts). Epilogue: f32 LDS exchange of
// complementary n-halves; wave0 finishes tokens 0..31, wave1 32..63.
// ---------------------------------------------------------------------------
__global__ __launch_bounds__(128, 3) void mlp_kernel(
    const float* __restrict__ it_g, const float* __restrict__ mask_g,
    const float* __restrict__ au_g, const unsigned short* __restrict__ ctxb,
    const unsigned short* __restrict__ wp,
    const float* __restrict__ b1, const float* __restrict__ b2,
    const float* __restrict__ b3, float* __restrict__ out)
{
    __shared__ __align__(16) unsigned short Acts[64 * ASTR];   // 25.1 KB

    const int tid = threadIdx.x;
    const int lane = tid & 63;
    const int wv = tid >> 6;
    const int gq = lane >> 4;
    const int cl = lane & 15;
    const long tile = (long)blockIdx.x * 64;
    const int b = (int)(tile >> 12);
    const int nbase = wv * 6;

    unsigned short* A0 = Acts;            // stride A0STR view, rows 0..63
    float* X = (float*)Acts;              // f32 exchange view (epilogue)

    // ---- stage layer-1 input: ctx cols 0..31, age col 32, zeros 33..63 ----
    {
        int tok = tid >> 1, half = tid & 1;
        const unsigned short* src = ctxb + (tile + tok) * Dn + half * 16;
        *(short8v*)(A0 + tok * A0STR + half * 16)     = *(const short8v*)src;
        *(short8v*)(A0 + tok * A0STR + half * 16 + 8) = *(const short8v*)(src + 8);
        short8v z = {0, 0, 0, 0, 0, 0, 0, 0};
        *(short8v*)(A0 + tok * A0STR + 40 + half * 16) = z;
        if (half == 0) {
            float itv = it_g[tile + tok];
            float auv = au_g[tile + tok];
            z[0] = (short)f2bf(__logf(fmaf(-auv, itv, itv) + 1e-8f));
        }
        *(short8v*)(A0 + tok * A0STR + 32 + half * 16) = z;
    }
    __syncthreads();

    f32x4 acc[6][4];

    auto run_layer = [&](auto NKC, const unsigned short* ap, int astride,
                         const unsigned short* wpl, const float* __restrict__ bias) {
        constexpr int nk = NKC.value;
#pragma unroll
        for (int j = 0; j < 6; ++j) {
            float bb = bias[(nbase + j) * 16 + cl];
#pragma unroll
            for (int m = 0; m < 4; ++m) acc[j][m] = (f32x4){bb, bb, bb, bb};
        }
#pragma unroll
        for (int ks = 0; ks < nk; ++ks) {
            short8v af[4];
#pragma unroll
            for (int m = 0; m < 4; ++m)
                af[m] = *(const short8v*)(ap + (m * 16 + cl) * astride + ks * 32 + 8 * gq);
            const unsigned short* wk = wpl + ((size_t)ks * 12 + nbase) * 512 + lane * 8;
#pragma unroll
            for (int j = 0; j < 6; ++j) {
                short8v bfv = *(const short8v*)(wk + j * 512);
#pragma unroll
                for (int m = 0; m < 4; ++m)
                    acc[j][m] = __builtin_amdgcn_mfma_f32_16x16x32_bf16(af[m], bfv, acc[j][m], 0, 0, 0);
            }
        }
    };

    auto store_h = [&]() {
#pragma unroll
        for (int j = 0; j < 6; ++j) {
            int col = (nbase + j) * 16 + cl;
#pragma unroll
            for (int m = 0; m < 4; ++m)
#pragma unroll
                for (int r = 0; r < 4; ++r)
                    Acts[(m * 16 + 4 * gq + r) * ASTR + col] = f2bf(fmaxf(acc[j][m][r], 0.0f));
        }
    };

    run_layer(std::integral_constant<int, 2>{}, A0, A0STR, wp, b1);
    __syncthreads();                 // all A0 reads done
    store_h();
    __syncthreads();                 // L1 outputs visible
    run_layer(std::integral_constant<int, 6>{}, Acts, ASTR, wp + 24 * 512, b2);
    __syncthreads();                 // all L2 input reads done
    store_h();
    __syncthreads();                 // L2 outputs visible
    run_layer(std::integral_constant<int, 6>{}, Acts, ASTR, wp + 96 * 512, b3);
    __syncthreads();                 // all L3 input reads done; Acts reusable

    // ---- exchange: each wave gives its accs for the OTHER wave's tokens ----
    if (wv == 0) {
#pragma unroll
        for (int j = 0; j < 6; ++j) {
            *(f32x4*)(X + ((12 + j) * 64 + lane) * 4) = acc[j][2];
            *(f32x4*)(X + ((18 + j) * 64 + lane) * 4) = acc[j][3];
        }
    } else {
#pragma unroll
        for (int j = 0; j < 6; ++j) {
            *(f32x4*)(X + ((0 + j) * 64 + lane) * 4) = acc[j][0];
            *(f32x4*)(X + ((6 + j) * 64 + lane) * 4) = acc[j][1];
        }
    }
    __syncthreads();

    float psum = 0.0f;
    auto do_epi = [&](auto MC) {
        constexpr int m = MC.value;
        f32x4 ac[12];
#pragma unroll
        for (int j = 0; j < 6; ++j) {
            f32x4 own = acc[j][m];
            f32x4 oth = *(const f32x4*)(X + ((m * 6 + j) * 64 + lane) * 4);
            ac[j]     = (wv == 0) ? own : oth;
            ac[6 + j] = (wv == 0) ? oth : own;
        }
        const long tm = tile + m * 16 + 4 * gq;
        f32x4 it4 = *(const f32x4*)(it_g   + tm);
        f32x4 au4 = *(const f32x4*)(au_g   + tm);
        f32x4 mk4 = *(const f32x4*)(mask_g + tm);
#pragma unroll
        for (int r = 0; r < 4; ++r) {
            float lg0 = ac[8][r], lg1 = ac[9][r], lg2 = ac[10][r], lg3 = ac[11][r];
            float m1 = fmaxf(fmaxf(lg0, lg1), fmaxf(lg2, lg3));
#pragma unroll
            for (int mm = 1; mm < 16; mm <<= 1) m1 = fmaxf(m1, __shfl_xor(m1, mm, 64));
            float se = __expf(lg0 - m1) + __expf(lg1 - m1) + __expf(lg2 - m1) + __expf(lg3 - m1);
#pragma unroll
            for (int mm = 1; mm < 16; mm <<= 1) se += __shfl_xor(se, mm, 64);
            float lse1 = m1 + __logf(se);

            float itv = it4[r], auv = au4[r];
            float y = __logf(fmaxf(itv * auv, 1e-10f));   // resid = it*au

            float comp[4];
            float m2 = -1e30f;
#pragma unroll
            for (int nb = 0; nb < 4; ++nb) {
                float loc = ac[nb][r];
                float lsr = fminf(fmaxf(ac[4 + nb][r], -5.0f), 3.0f);
                float zs = (y - loc) * __expf(-lsr);
                comp[nb] = (ac[8 + nb][r] - lse1) - lsr - HALF_LOG2PI - 0.5f * zs * zs;
                m2 = fmaxf(m2, comp[nb]);
            }
#pragma unroll
            for (int mm = 1; mm < 16; mm <<= 1) m2 = fmaxf(m2, __shfl_xor(m2, mm, 64));
            float se2 = __expf(comp[0] - m2) + __expf(comp[1] - m2) +
                        __expf(comp[2] - m2) + __expf(comp[3] - m2);
#pragma unroll
            for (int mm = 1; mm < 16; mm <<= 1) se2 += __shfl_xor(se2, mm, 64);
            float lp = (m2 + __logf(se2) - y) * mk4[r];
            if (cl == 0) psum += lp;
        }
    };

    if (wv == 0) {
        do_epi(std::integral_constant<int, 0>{});
        do_epi(std::integral_constant<int, 1>{});
    } else {
        do_epi(std::integral_constant<int, 2>{});
        do_epi(std::integral_constant<int, 3>{});
    }

#pragma unroll
    for (int mm = 1; mm < 64; mm <<= 1) psum += __shfl_xor(psum, mm, 64);
    __syncthreads();
    if (lane == 0) {
        float* WS = (float*)Acts;
        WS[wv] = psum;
    }
    __syncthreads();
    if (tid == 0) atomicAdd(out + b, ((float*)Acts)[0] + ((float*)Acts)[1]);
}

// ---------------------------------------------------------------------------
extern "C" void kernel_launch(void* const* d_in, const int* in_sizes, int n_in,
                              void* d_out, int out_size, void* d_ws, size_t ws_size,
                              hipStream_t stream) {
    const float* it_g  = (const float*)d_in[0];
    const float* mask  = (const float*)d_in[1];
    const float* au    = (const float*)d_in[2];
    const float* W     = (const float*)d_in[3];
    const float* v     = (const float*)d_in[4];
    const float* bia   = (const float*)d_in[5];
    const float* cinit = (const float*)d_in[6];
    const float* W1    = (const float*)d_in[7];
    const float* b1    = (const float*)d_in[8];
    const float* W2    = (const float*)d_in[9];
    const float* b2    = (const float*)d_in[10];
    const float* W3    = (const float*)d_in[11];
    const float* b3    = (const float*)d_in[12];
    float* out = (float*)d_out;

    unsigned short* ctxb = (unsigned short*)d_ws;                 // 32 MB
    unsigned short* wp   = ctxb + (size_t)Bn * Sn * Dn;           // 168 KB

    hipMemsetAsync(d_out, 0, (size_t)out_size * sizeof(float), stream);

    pack_weights<<<168, 64, 0, stream>>>(W1, W2, W3, wp);
    recurrence_kernel<<<(Bn * Dn * CH) / 256, 256, 0, stream>>>(
        it_g, W, v, bia, cinit, ctxb);
    mlp_kernel<<<(Bn * Sn) / 64, 128, 0, stream>>>(
        it_g, mask, au, ctxb, wp, b1, b2, b3, out);
}